// Round 4
// baseline (3248.867 us; speedup 1.0000x reference)
//
#include <hip/hip_runtime.h>
#include <hip/hip_bf16.h>
#include <cstdint>

typedef __hip_bfloat16 bf16;
#define DEVI __device__ __forceinline__

DEVI float b2f(bf16 v){ return __bfloat162float(v); }
DEVI bf16 f2b(float v){ return __float2bfloat16(v); }
DEVI float lrelu(float x, float s){ return x > 0.f ? x : x * s; }

// dtype-adaptive accessors: f==1 -> bf16 data, f==0 -> float32 data
DEVI float ldf(const void* p, size_t i, int f){
  return f ? b2f(((const bf16*)p)[i]) : ((const float*)p)[i];
}
DEVI void stf(void* p, size_t i, int f, float v){
  if(f) ((bf16*)p)[i] = f2b(v); else ((float*)p)[i] = v;
}

DEVI float wave_sum(float v){
#pragma unroll
  for(int o = 32; o > 0; o >>= 1) v += __shfl_xor(v, o, 64);
  return v;
}
DEVI float wave_max(float v){
#pragma unroll
  for(int o = 32; o > 0; o >>= 1) v = fmaxf(v, __shfl_xor(v, o, 64));
  return v;
}

// ---- dtype detector ---------------------------------------------------------
__global__ void k_detect(const uint32_t* __restrict__ xf, int* flag){
  const int lane = threadIdx.x & 63;
  float cnt = 0.f;
  for(int i = lane; i < 256; i += 64){
    uint32_t e = (xf[i] >> 7) & 0xFF;
    if(e >= 100 && e <= 140) cnt += 1.f;
  }
  cnt = wave_sum(cnt);
  if(lane == 0 && blockIdx.x == 0) *flag = (cnt > 180.f) ? 1 : 0;
}

// ---- encoder ----------------------------------------------------------------
__global__ __launch_bounds__(256) void k_encoder(
    const void* __restrict__ xf, const int* __restrict__ ids,
    const void* __restrict__ emb, const void* __restrict__ win,
    const void* __restrict__ bin, float* __restrict__ x,
    const int* __restrict__ flagp, int N)
{
  __shared__ float W[128*64];
  __shared__ float B[64];
  __shared__ float XR[4][128];
  const int t = threadIdx.x;
  const int f = *flagp;
  for(int i = t; i < 128*64; i += 256) W[i] = ldf(win, i, f);
  if(t < 64) B[t] = ldf(bin, t, f);
  __syncthreads();
  const int w = t >> 6, lane = t & 63;
  for(int base = blockIdx.x*4; base < N; base += gridDim.x*4){
    const int node = base + w;
    if(node < N){
      for(int k = lane; k < 128; k += 64){
        float v;
        if(k < 124) v = ldf(xf, (size_t)node*124 + k, f);
        else        v = ldf(emb, (size_t)ids[node]*4 + (k-124), f);
        XR[w][k] = v;
      }
      float acc = B[lane];
#pragma unroll 8
      for(int k = 0; k < 128; k++) acc = fmaf(XR[w][k], W[k*64+lane], acc);
      x[(size_t)node*64 + lane] = lrelu(acc, 0.01f);
    }
  }
}

// ---- per-layer linear -------------------------------------------------------
__global__ __launch_bounds__(256) void k_linear(
    const float* __restrict__ x, const void* __restrict__ lw,
    const void* __restrict__ lb, float* __restrict__ g,
    const int* __restrict__ flagp, int layer, int N)
{
  __shared__ float W[64*64];
  __shared__ float B[64];
  __shared__ float XR[4][64];
  const int t = threadIdx.x;
  const int f = *flagp;
  const size_t wofs = (size_t)layer*64*64, bofs = (size_t)layer*64;
  for(int i = t; i < 64*64; i += 256) W[i] = ldf(lw, wofs + i, f);
  if(t < 64) B[t] = ldf(lb, bofs + t, f);
  __syncthreads();
  const int w = t >> 6, lane = t & 63;
  for(int base = blockIdx.x*4; base < N; base += gridDim.x*4){
    const int node = base + w;
    if(node < N){
      XR[w][lane] = x[(size_t)node*64 + lane];
      float acc = B[lane];
#pragma unroll 8
      for(int k = 0; k < 64; k++) acc = fmaf(XR[w][k], W[k*64+lane], acc);
      g[(size_t)node*64 + lane] = acc;
    }
  }
}

// ---- CSR build --------------------------------------------------------------
__global__ void k_deg_init(int* deg, int N){
  int i = blockIdx.x*blockDim.x + threadIdx.x;
  if(i < N) deg[i] = 1;  // self-loop
}
__global__ void k_deg_count(const int* __restrict__ dst, int* deg, int E){
  int j = blockIdx.x*blockDim.x + threadIdx.x;
  if(j < E) atomicAdd(&deg[dst[j]], 1);
}
__global__ __launch_bounds__(256) void k_scan_partial(const int* __restrict__ deg, int* partial, int N){
  __shared__ int red[256];
  const int c = blockIdx.x, base = c*1024, t = threadIdx.x;
  int s = 0;
  for(int i = t; i < 1024; i += 256){ int idx = base+i; s += (idx < N) ? deg[idx] : 0; }
  red[t] = s; __syncthreads();
  for(int o = 128; o > 0; o >>= 1){ if(t < o) red[t] += red[t+o]; __syncthreads(); }
  if(t == 0) partial[c] = red[0];
}
__global__ void k_scan_top(int* partial, int nchunks){
  if(threadIdx.x == 0 && blockIdx.x == 0){
    int run = 0;
    for(int i = 0; i < nchunks; i++){ int v = partial[i]; partial[i] = run; run += v; }
  }
}
__global__ __launch_bounds__(256) void k_scan_final(
    const int* __restrict__ deg, const int* __restrict__ partial,
    int* __restrict__ off, int* __restrict__ cur, int N)
{
  __shared__ int vals[1024];
  __shared__ int tsum[256];
  const int c = blockIdx.x, base = c*1024, t = threadIdx.x;
  for(int i = t; i < 1024; i += 256){ int idx = base+i; vals[i] = (idx < N) ? deg[idx] : 0; }
  __syncthreads();
  int a0 = vals[t*4], a1 = vals[t*4+1], a2 = vals[t*4+2], a3 = vals[t*4+3];
  int s = a0+a1+a2+a3;
  tsum[t] = s; __syncthreads();
  for(int o = 1; o < 256; o <<= 1){
    int v = (t >= o) ? tsum[t-o] : 0;
    __syncthreads();
    tsum[t] += v;
    __syncthreads();
  }
  int excl = tsum[t] - s + partial[c];
  int o0 = excl, o1 = o0+a0, o2 = o1+a1, o3 = o2+a2;
  int idx = base + t*4;
  if(idx   < N){ off[idx]   = o0; cur[idx]   = o0; }
  if(idx+1 < N){ off[idx+1] = o1; cur[idx+1] = o1; }
  if(idx+2 < N){ off[idx+2] = o2; cur[idx+2] = o2; }
  if(idx+3 < N){ off[idx+3] = o3; cur[idx+3] = o3; }
}
// also emits inverse permutation: inv[orig_edge_id] = csr position
__global__ void k_scatter(const int* __restrict__ src, const int* __restrict__ dst,
                          int* cur, int* __restrict__ inv, int* __restrict__ csrc,
                          int E, int N){
  int j = blockIdx.x*blockDim.x + threadIdx.x;
  int T = E + N;
  if(j >= T) return;
  int s, d;
  if(j < E){ s = src[j]; d = dst[j]; } else { s = j - E; d = s; }
  int p = atomicAdd(&cur[d], 1);
  inv[j] = p; csrc[p] = s;
}

// ---- fused GATv2 (two unrolled passes, max-MLP) + GraphNorm stats -----------
__global__ __launch_bounds__(256) void k_gat(
    const float* __restrict__ g, const int* __restrict__ off,
    const int* __restrict__ deg, const int* __restrict__ csrc,
    const void* __restrict__ att, const void* __restrict__ convb,
    float* __restrict__ xout, float* __restrict__ ws_alpha,
    float* __restrict__ stats, const int* __restrict__ flagp, int layer, int N)
{
  __shared__ float att_s[64];
  __shared__ float gd_s[4][64];
  __shared__ float sv[4][64], sv2[4][64];
  const int t = threadIdx.x, w = t >> 6, lane = t & 63;
  const int q = lane >> 4, L = lane & 15;
  const int f = *flagp;
  const size_t pofs = (size_t)layer*64;
  if(t < 64) att_s[t] = ldf(att, pofs + t, f);
  const int node = blockIdx.x*4 + w;
  const bool act = node < N;
  const int nc = act ? node : N-1;
  gd_s[w][lane] = g[(size_t)nc*64 + lane];
  sv[w][lane] = 0.f; sv2[w][lane] = 0.f;
  __syncthreads();

  const int o = off[nc];
  const int d = act ? deg[nc] : 1;
  const int jme = lane < d ? lane : d-1;     // clamped edge idx for this lane
  const int sj = csrc[o + jme];              // coalesced

  if(d <= 64){
    // ---------- pass A: lane-per-edge logits, 16 loads in flight/lane -------
    float4 r0,r1,r2,r3,r4,r5,r6,r7,r8,r9,r10,r11,r12,r13,r14,r15;
    const float4* gr = (const float4*)(g + (size_t)sj*64);
    r0=gr[0]; r1=gr[1]; r2=gr[2]; r3=gr[3]; r4=gr[4]; r5=gr[5]; r6=gr[6]; r7=gr[7];
    r8=gr[8]; r9=gr[9]; r10=gr[10]; r11=gr[11]; r12=gr[12]; r13=gr[13]; r14=gr[14]; r15=gr[15];
    float e = 0.f;
    const float4* gd4 = (const float4*)(&gd_s[w][0]);
    const float4* at4 = (const float4*)(&att_s[0]);
#define ECHUNK(RC, c) { float4 gdc = gd4[c]; float4 ac = at4[c];            \
    e += lrelu(RC.x+gdc.x,0.2f)*ac.x + lrelu(RC.y+gdc.y,0.2f)*ac.y         \
       + lrelu(RC.z+gdc.z,0.2f)*ac.z + lrelu(RC.w+gdc.w,0.2f)*ac.w; }
    ECHUNK(r0,0) ECHUNK(r1,1) ECHUNK(r2,2) ECHUNK(r3,3)
    ECHUNK(r4,4) ECHUNK(r5,5) ECHUNK(r6,6) ECHUNK(r7,7)
    ECHUNK(r8,8) ECHUNK(r9,9) ECHUNK(r10,10) ECHUNK(r11,11)
    ECHUNK(r12,12) ECHUNK(r13,13) ECHUNK(r14,14) ECHUNK(r15,15)
#undef ECHUNK
    if(lane >= d) e = -1e30f;
    // ---------- softmax over the segment ------------------------------------
    const float m = wave_max(e);
    const float a = __expf(e - m);
    const float s = wave_sum(a);
    const float alpha = a / s;                // 0 for clamped lanes
    if(act && lane < d) ws_alpha[o + lane] = alpha;   // coalesced CSR-order
    // ---------- pass B: quarter-wave aggregation, 16 loads in flight --------
    float4 acc = {0.f,0.f,0.f,0.f};
#pragma unroll
    for(int i = 0; i < 16; i++){
      const int j = 4*i + q;
      const int s2 = __shfl(sj, j, 64);
      const float aj = __shfl(alpha, j, 64);
      const float4 gs = *(const float4*)(g + (size_t)s2*64 + 4*L);
      acc.x = fmaf(aj, gs.x, acc.x);
      acc.y = fmaf(aj, gs.y, acc.y);
      acc.z = fmaf(aj, gs.z, acc.z);
      acc.w = fmaf(aj, gs.w, acc.w);
    }
#pragma unroll
    for(int ofs = 16; ofs <= 32; ofs <<= 1){
      acc.x += __shfl_xor(acc.x, ofs, 64);
      acc.y += __shfl_xor(acc.y, ofs, 64);
      acc.z += __shfl_xor(acc.z, ofs, 64);
      acc.w += __shfl_xor(acc.w, ofs, 64);
    }
    float4 v = {0.f,0.f,0.f,0.f};
    if(act){
      v.x = acc.x + ldf(convb, pofs + 4*L+0, f);
      v.y = acc.y + ldf(convb, pofs + 4*L+1, f);
      v.z = acc.z + ldf(convb, pofs + 4*L+2, f);
      v.w = acc.w + ldf(convb, pofs + 4*L+3, f);
      if(q == 0) *(float4*)(xout + (size_t)nc*64 + 4*L) = v;
    }
    if(q == 0){
      sv [w][4*L+0]=v.x;     sv [w][4*L+1]=v.y;     sv [w][4*L+2]=v.z;     sv [w][4*L+3]=v.w;
      sv2[w][4*L+0]=v.x*v.x; sv2[w][4*L+1]=v.y*v.y; sv2[w][4*L+2]=v.z*v.z; sv2[w][4*L+3]=v.w*v.w;
    }
  } else {
    // ---------- slow path (deg > 64, statistically never) -------------------
    const float gdl = gd_s[w][lane];
    const float al  = att_s[lane];
    float m = -1e30f;
    for(int j = 0; j < d; j++){
      const int s = csrc[o+j];
      const float gs = g[(size_t)s*64 + lane];
      const float e = wave_sum(lrelu(gs + gdl, 0.2f) * al);
      if(lane == 0) ws_alpha[o+j] = e;       // raw logits temporarily
      m = fmaxf(m, e);
    }
    float sp = 0.f;
    for(int j = lane; j < d; j += 64) sp += __expf(ws_alpha[o+j] - m);
    sp = wave_sum(sp);
    const float inv = 1.f / sp;
    for(int j = lane; j < d; j += 64) ws_alpha[o+j] = __expf(ws_alpha[o+j] - m) * inv;
    float accl = 0.f;
    for(int j = 0; j < d; j++){
      const int s = csrc[o+j];
      accl = fmaf(ws_alpha[o+j], g[(size_t)s*64 + lane], accl);
    }
    const float vl = accl + ldf(convb, pofs + lane, f);
    if(act) xout[(size_t)nc*64 + lane] = vl;
    sv[w][lane] = vl; sv2[w][lane] = vl*vl;
  }
  __syncthreads();
  if(w == 0){
    float a = sv[0][lane]+sv[1][lane]+sv[2][lane]+sv[3][lane];
    float b = sv2[0][lane]+sv2[1][lane]+sv2[2][lane]+sv2[3][lane];
    atomicAdd(&stats[lane],    a);
    atomicAdd(&stats[64+lane], b);
  }
}

// ---- alpha permutation: coalesced write, small-working-set gather -----------
__global__ __launch_bounds__(256) void k_alpha_perm(
    const float* __restrict__ ws_alpha, const int* __restrict__ inv,
    void* __restrict__ out, size_t a_base, const int* __restrict__ flagp, int T)
{
  const int f = *flagp;
  int i = blockIdx.x*blockDim.x + threadIdx.x;
  if(i < T) stf(out, a_base + i, f, ws_alpha[inv[i]]);
}

// ---- GraphNorm apply --------------------------------------------------------
__global__ void k_zero_stats(float* stats){ stats[threadIdx.x] = 0.f; }

__global__ __launch_bounds__(256) void k_gn_apply(
    float* __restrict__ x, const float* __restrict__ stats,
    const void* __restrict__ gw, const void* __restrict__ gb,
    const void* __restrict__ gms, void* __restrict__ out,
    size_t x_base, size_t h_base, const int* __restrict__ flagp,
    int N, int layer, float invN)
{
  const int f = *flagp;
  const int lane = threadIdx.x & 63;
  const size_t pofs = (size_t)layer*64;
  const float mean = stats[lane] * invN;
  const float ex2  = stats[64+lane] * invN;
  const float c    = mean * ldf(gms, pofs + lane, f);
  const float var  = ex2 - 2.f*c*mean + c*c;   // E[(x-c)^2]
  const float a    = ldf(gw, pofs + lane, f) / sqrtf(var + 1e-5f);
  const float bb   = ldf(gb, pofs + lane, f);
  const size_t total = (size_t)N * 64;
  for(size_t idx = (size_t)blockIdx.x*256 + threadIdx.x; idx < total;
      idx += (size_t)gridDim.x*256){
    float v = (x[idx] - c) * a + bb;
    v = lrelu(v, 0.01f);
    x[idx] = v;
    float hv = 0.5f*v + (layer == 0 ? 0.f : ldf(out, h_base + idx, f));
    stf(out, h_base + idx, f, hv);
    if(layer == 3) stf(out, x_base + idx, f, v);
  }
}

// ---- host launch ------------------------------------------------------------
extern "C" void kernel_launch(void* const* d_in, const int* in_sizes, int n_in,
                              void* d_out, int out_size, void* d_ws, size_t ws_size,
                              hipStream_t stream) {
  const void* xf   = d_in[0];
  const int*  ids  = (const int*)d_in[1];
  const int*  eidx = (const int*)d_in[2];
  const void* emb  = d_in[3];
  const void* win  = d_in[4];
  const void* bin  = d_in[5];
  const void* lw   = d_in[6];
  const void* lb   = d_in[7];
  const void* att  = d_in[8];
  const void* cb   = d_in[9];
  const void* gw   = d_in[10];
  const void* gb   = d_in[11];
  const void* gms  = d_in[12];

  const int N = in_sizes[1];
  const int E = in_sizes[2] / 2;
  const int T = E + N;
  const int* srcp = eidx;
  const int* dstp = eidx + E;

  // workspace carve (~73 MB)
  char* p = (char*)d_ws;
  float* x  = (float*)p; p += (size_t)N*64*4;
  float* g  = (float*)p; p += (size_t)N*64*4;
  int* deg  = (int*)p;   p += ((size_t)N*4 + 63) & ~63ull;
  int* off  = (int*)p;   p += ((size_t)N*4 + 63) & ~63ull;
  int* cur  = (int*)p;   p += ((size_t)N*4 + 63) & ~63ull;
  int* inv  = (int*)p;   p += ((size_t)T*4 + 63) & ~63ull;
  int* csrc = (int*)p;   p += ((size_t)T*4 + 63) & ~63ull;
  float* ws_alpha = (float*)p; p += ((size_t)T*4 + 63) & ~63ull;
  int* partial = (int*)p; p += 4096;
  float* stats = (float*)p; p += 512;
  int* flag = (int*)p;    p += 64;

  const size_t x_base = 0;
  const size_t h_base = (size_t)N*64;
  const size_t a_base = (size_t)2*N*64;

  k_detect<<<1, 64, 0, stream>>>((const uint32_t*)xf, flag);
  k_encoder<<<2048, 256, 0, stream>>>(xf, ids, emb, win, bin, x, flag, N);

  k_deg_init <<<(N+255)/256, 256, 0, stream>>>(deg, N);
  k_deg_count<<<(E+255)/256, 256, 0, stream>>>(dstp, deg, E);
  const int nchunks = (N + 1023) / 1024;
  k_scan_partial<<<nchunks, 256, 0, stream>>>(deg, partial, N);
  k_scan_top    <<<1, 1, 0, stream>>>(partial, nchunks);
  k_scan_final  <<<nchunks, 256, 0, stream>>>(deg, partial, off, cur, N);
  k_scatter     <<<(T+255)/256, 256, 0, stream>>>(srcp, dstp, cur, inv, csrc, E, N);

  for(int l = 0; l < 4; l++){
    k_zero_stats<<<1, 128, 0, stream>>>(stats);
    k_linear<<<2048, 256, 0, stream>>>(x, lw, lb, g, flag, l, N);
    k_gat<<<(N+3)/4, 256, 0, stream>>>(g, off, deg, csrc, att, cb, x,
                                       ws_alpha, stats, flag, l, N);
    k_alpha_perm<<<(T+255)/256, 256, 0, stream>>>(ws_alpha, inv, d_out,
                                                  a_base + (size_t)l*T, flag, T);
    k_gn_apply<<<1024, 256, 0, stream>>>(x, stats, gw, gb, gms, d_out,
                                         x_base, h_base, flag, N, l, 1.0f/(float)N);
  }
}

// Round 5
// 3231.858 us; speedup vs baseline: 1.0053x; 1.0053x over previous
//
#include <hip/hip_runtime.h>
#include <hip/hip_bf16.h>
#include <cstdint>

typedef __hip_bfloat16 bf16;
#define DEVI __device__ __forceinline__

DEVI float b2f(bf16 v){ return __bfloat162float(v); }
DEVI bf16 f2b(float v){ return __float2bfloat16(v); }
DEVI float lrelu(float x, float s){ return x > 0.f ? x : x * s; }

// dtype-adaptive accessors: f==1 -> bf16 data, f==0 -> float32 data
DEVI float ldf(const void* p, size_t i, int f){
  return f ? b2f(((const bf16*)p)[i]) : ((const float*)p)[i];
}
DEVI void stf(void* p, size_t i, int f, float v){
  if(f) ((bf16*)p)[i] = f2b(v); else ((float*)p)[i] = v;
}

DEVI float wave_sum(float v){
#pragma unroll
  for(int o = 32; o > 0; o >>= 1) v += __shfl_xor(v, o, 64);
  return v;
}
DEVI float wave_max(float v){
#pragma unroll
  for(int o = 32; o > 0; o >>= 1) v = fmaxf(v, __shfl_xor(v, o, 64));
  return v;
}
// sum within 16-lane quarter (4 quarters reduce simultaneously)
DEVI float qsum(float v){
  v += __shfl_xor(v, 1, 64);
  v += __shfl_xor(v, 2, 64);
  v += __shfl_xor(v, 4, 64);
  v += __shfl_xor(v, 8, 64);
  return v;
}

// ---- dtype detector ---------------------------------------------------------
__global__ void k_detect(const uint32_t* __restrict__ xf, int* flag){
  const int lane = threadIdx.x & 63;
  float cnt = 0.f;
  for(int i = lane; i < 256; i += 64){
    uint32_t e = (xf[i] >> 7) & 0xFF;
    if(e >= 100 && e <= 140) cnt += 1.f;
  }
  cnt = wave_sum(cnt);
  if(lane == 0 && blockIdx.x == 0) *flag = (cnt > 180.f) ? 1 : 0;
}

// ---- encoder ----------------------------------------------------------------
__global__ __launch_bounds__(256) void k_encoder(
    const void* __restrict__ xf, const int* __restrict__ ids,
    const void* __restrict__ emb, const void* __restrict__ win,
    const void* __restrict__ bin, float* __restrict__ x,
    const int* __restrict__ flagp, int N)
{
  __shared__ float W[128*64];
  __shared__ float B[64];
  __shared__ float XR[4][128];
  const int t = threadIdx.x;
  const int f = *flagp;
  for(int i = t; i < 128*64; i += 256) W[i] = ldf(win, i, f);
  if(t < 64) B[t] = ldf(bin, t, f);
  __syncthreads();
  const int w = t >> 6, lane = t & 63;
  for(int base = blockIdx.x*4; base < N; base += gridDim.x*4){
    const int node = base + w;
    if(node < N){
      for(int k = lane; k < 128; k += 64){
        float v;
        if(k < 124) v = ldf(xf, (size_t)node*124 + k, f);
        else        v = ldf(emb, (size_t)ids[node]*4 + (k-124), f);
        XR[w][k] = v;
      }
      float acc = B[lane];
#pragma unroll 8
      for(int k = 0; k < 128; k++) acc = fmaf(XR[w][k], W[k*64+lane], acc);
      x[(size_t)node*64 + lane] = lrelu(acc, 0.01f);
    }
  }
}

// ---- per-layer linear -------------------------------------------------------
__global__ __launch_bounds__(256) void k_linear(
    const float* __restrict__ x, const void* __restrict__ lw,
    const void* __restrict__ lb, float* __restrict__ g,
    const int* __restrict__ flagp, int layer, int N)
{
  __shared__ float W[64*64];
  __shared__ float B[64];
  __shared__ float XR[4][64];
  const int t = threadIdx.x;
  const int f = *flagp;
  const size_t wofs = (size_t)layer*64*64, bofs = (size_t)layer*64;
  for(int i = t; i < 64*64; i += 256) W[i] = ldf(lw, wofs + i, f);
  if(t < 64) B[t] = ldf(lb, bofs + t, f);
  __syncthreads();
  const int w = t >> 6, lane = t & 63;
  for(int base = blockIdx.x*4; base < N; base += gridDim.x*4){
    const int node = base + w;
    if(node < N){
      XR[w][lane] = x[(size_t)node*64 + lane];
      float acc = B[lane];
#pragma unroll 8
      for(int k = 0; k < 64; k++) acc = fmaf(XR[w][k], W[k*64+lane], acc);
      g[(size_t)node*64 + lane] = acc;
    }
  }
}

// ---- CSR build --------------------------------------------------------------
__global__ void k_deg_init(int* deg, int N){
  int i = blockIdx.x*blockDim.x + threadIdx.x;
  if(i < N) deg[i] = 1;  // self-loop
}
__global__ void k_deg_count(const int* __restrict__ dst, int* deg, int E){
  int j = blockIdx.x*blockDim.x + threadIdx.x;
  if(j < E) atomicAdd(&deg[dst[j]], 1);
}
__global__ __launch_bounds__(256) void k_scan_partial(const int* __restrict__ deg, int* partial, int N){
  __shared__ int red[256];
  const int c = blockIdx.x, base = c*1024, t = threadIdx.x;
  int s = 0;
  for(int i = t; i < 1024; i += 256){ int idx = base+i; s += (idx < N) ? deg[idx] : 0; }
  red[t] = s; __syncthreads();
  for(int o = 128; o > 0; o >>= 1){ if(t < o) red[t] += red[t+o]; __syncthreads(); }
  if(t == 0) partial[c] = red[0];
}
__global__ void k_scan_top(int* partial, int nchunks){
  if(threadIdx.x == 0 && blockIdx.x == 0){
    int run = 0;
    for(int i = 0; i < nchunks; i++){ int v = partial[i]; partial[i] = run; run += v; }
  }
}
__global__ __launch_bounds__(256) void k_scan_final(
    const int* __restrict__ deg, const int* __restrict__ partial,
    int* __restrict__ off, int* __restrict__ cur, int N)
{
  __shared__ int vals[1024];
  __shared__ int tsum[256];
  const int c = blockIdx.x, base = c*1024, t = threadIdx.x;
  for(int i = t; i < 1024; i += 256){ int idx = base+i; vals[i] = (idx < N) ? deg[idx] : 0; }
  __syncthreads();
  int a0 = vals[t*4], a1 = vals[t*4+1], a2 = vals[t*4+2], a3 = vals[t*4+3];
  int s = a0+a1+a2+a3;
  tsum[t] = s; __syncthreads();
  for(int o = 1; o < 256; o <<= 1){
    int v = (t >= o) ? tsum[t-o] : 0;
    __syncthreads();
    tsum[t] += v;
    __syncthreads();
  }
  int excl = tsum[t] - s + partial[c];
  int o0 = excl, o1 = o0+a0, o2 = o1+a1, o3 = o2+a2;
  int idx = base + t*4;
  if(idx   < N){ off[idx]   = o0; cur[idx]   = o0; }
  if(idx+1 < N){ off[idx+1] = o1; cur[idx+1] = o1; }
  if(idx+2 < N){ off[idx+2] = o2; cur[idx+2] = o2; }
  if(idx+3 < N){ off[idx+3] = o3; cur[idx+3] = o3; }
}
// also emits inverse permutation: inv[orig_edge_id] = csr position
__global__ void k_scatter(const int* __restrict__ src, const int* __restrict__ dst,
                          int* cur, int* __restrict__ inv, int* __restrict__ csrc,
                          int E, int N){
  int j = blockIdx.x*blockDim.x + threadIdx.x;
  int T = E + N;
  if(j >= T) return;
  int s, d;
  if(j < E){ s = src[j]; d = dst[j]; } else { s = j - E; d = s; }
  int p = atomicAdd(&cur[d], 1);
  inv[j] = p; csrc[p] = s;
}

// ---- fused GATv2: single gather, quarter-wave rows, tiered unroll -----------
// Edge j handled by quarter q=j&3 at iteration i=j>>2; 16 lanes/quarter hold a
// full 64-ch row as float4 per lane. Rows stay in registers for the aggregate.
__global__ __launch_bounds__(256, 4) void k_gat(
    const float* __restrict__ g, const int* __restrict__ off,
    const int* __restrict__ deg, const int* __restrict__ csrc,
    const void* __restrict__ att, const void* __restrict__ convb,
    float* __restrict__ xout, float* __restrict__ ws_alpha,
    float* __restrict__ stats, const int* __restrict__ flagp, int layer, int N)
{
  __shared__ float sv[4][64], sv2[4][64];
  const int t = threadIdx.x, w = t >> 6, lane = t & 63;
  const int q = lane >> 4, L = lane & 15;
  const int f = *flagp;
  const size_t pofs = (size_t)layer*64;
  const int node = blockIdx.x*4 + w;
  const bool act = node < N;
  const int nc = act ? node : N-1;
  const int o = off[nc];
  const int d = act ? deg[nc] : 1;

  float4 attv;
  attv.x = ldf(att, pofs + 4*L+0, f); attv.y = ldf(att, pofs + 4*L+1, f);
  attv.z = ldf(att, pofs + 4*L+2, f); attv.w = ldf(att, pofs + 4*L+3, f);
  const float4 gdv = *(const float4*)(g + (size_t)nc*64 + 4*L);
  const int sreg = csrc[o + (lane < d ? lane : d-1)];   // coalesced

  if(d <= 64){
    float ereg = -1e30f;
    float alpha = 0.f;
    float4 acc = {0.f,0.f,0.f,0.f};

#define GAT_TIER(NIT) {                                                        \
    float4 gsv[NIT];                                                           \
    _Pragma("unroll")                                                          \
    for(int i = 0; i < NIT; i++){                                              \
      const int j = 4*i + q;                                                   \
      const int s2 = __shfl(sreg, j, 64);                                      \
      gsv[i] = make_float4(0.f,0.f,0.f,0.f);                                   \
      if(j < d) gsv[i] = *(const float4*)(g + (size_t)s2*64 + 4*L);            \
    }                                                                          \
    _Pragma("unroll")                                                          \
    for(int i = 0; i < NIT; i++){                                              \
      float pe = lrelu(gsv[i].x+gdv.x,0.2f)*attv.x                             \
               + lrelu(gsv[i].y+gdv.y,0.2f)*attv.y                             \
               + lrelu(gsv[i].z+gdv.z,0.2f)*attv.z                             \
               + lrelu(gsv[i].w+gdv.w,0.2f)*attv.w;                            \
      float e = qsum(pe);                                                      \
      if(4*i + q >= d) e = -1e30f;                                             \
      if(L == i) ereg = e;                                                     \
    }                                                                          \
    const float m  = wave_max(ereg);                                           \
    const float a0 = __expf(ereg - m);                                         \
    const float s0 = wave_sum(a0);                                             \
    alpha = a0 / s0;                                                           \
    _Pragma("unroll")                                                          \
    for(int i = 0; i < NIT; i++){                                              \
      const float aj = __shfl(alpha, (lane & 48) + i, 64);                     \
      acc.x = fmaf(aj, gsv[i].x, acc.x);                                       \
      acc.y = fmaf(aj, gsv[i].y, acc.y);                                       \
      acc.z = fmaf(aj, gsv[i].z, acc.z);                                       \
      acc.w = fmaf(aj, gsv[i].w, acc.w);                                       \
    } }

    if(d <= 16)      GAT_TIER(4)
    else if(d <= 32) GAT_TIER(8)
    else             GAT_TIER(16)
#undef GAT_TIER

    // cross-quarter channel reduction
#pragma unroll
    for(int ofs = 16; ofs <= 32; ofs <<= 1){
      acc.x += __shfl_xor(acc.x, ofs, 64);
      acc.y += __shfl_xor(acc.y, ofs, 64);
      acc.z += __shfl_xor(acc.z, ofs, 64);
      acc.w += __shfl_xor(acc.w, ofs, 64);
    }
    // alpha: lane (q,L) holds edge 4L+q
    const int j = 4*L + q;
    if(act && j < d) ws_alpha[o + j] = alpha;

    float4 v = {0.f,0.f,0.f,0.f};
    if(act){
      v.x = acc.x + ldf(convb, pofs + 4*L+0, f);
      v.y = acc.y + ldf(convb, pofs + 4*L+1, f);
      v.z = acc.z + ldf(convb, pofs + 4*L+2, f);
      v.w = acc.w + ldf(convb, pofs + 4*L+3, f);
      if(q == 0) *(float4*)(xout + (size_t)nc*64 + 4*L) = v;
    }
    if(q == 0){
      sv [w][4*L+0]=v.x;     sv [w][4*L+1]=v.y;     sv [w][4*L+2]=v.z;     sv [w][4*L+3]=v.w;
      sv2[w][4*L+0]=v.x*v.x; sv2[w][4*L+1]=v.y*v.y; sv2[w][4*L+2]=v.z*v.z; sv2[w][4*L+3]=v.w*v.w;
    }
  } else {
    // ---------- slow path (deg > 64, statistically never) -------------------
    const float gdl = g[(size_t)nc*64 + lane];
    const float al  = ldf(att, pofs + lane, f);
    float m = -1e30f;
    for(int jj = 0; jj < d; jj++){
      const int s = csrc[o+jj];
      const float gs = g[(size_t)s*64 + lane];
      const float e = wave_sum(lrelu(gs + gdl, 0.2f) * al);
      if(lane == 0) ws_alpha[o+jj] = e;       // raw logits temporarily
      m = fmaxf(m, e);
    }
    float sp = 0.f;
    for(int jj = lane; jj < d; jj += 64) sp += __expf(ws_alpha[o+jj] - m);
    sp = wave_sum(sp);
    const float inv = 1.f / sp;
    for(int jj = lane; jj < d; jj += 64) ws_alpha[o+jj] = __expf(ws_alpha[o+jj] - m) * inv;
    float accl = 0.f;
    for(int jj = 0; jj < d; jj++){
      const int s = csrc[o+jj];
      accl = fmaf(ws_alpha[o+jj], g[(size_t)s*64 + lane], accl);
    }
    const float vl = accl + ldf(convb, pofs + lane, f);
    if(act) xout[(size_t)nc*64 + lane] = vl;
    sv[w][lane] = vl; sv2[w][lane] = vl*vl;
  }
  __syncthreads();
  if(w == 0){
    float a = sv[0][lane]+sv[1][lane]+sv[2][lane]+sv[3][lane];
    float b = sv2[0][lane]+sv2[1][lane]+sv2[2][lane]+sv2[3][lane];
    atomicAdd(&stats[lane],    a);
    atomicAdd(&stats[64+lane], b);
  }
}

// ---- alpha permutation: coalesced write, small-working-set gather -----------
__global__ __launch_bounds__(256) void k_alpha_perm(
    const float* __restrict__ ws_alpha, const int* __restrict__ inv,
    void* __restrict__ out, size_t a_base, const int* __restrict__ flagp, int T)
{
  const int f = *flagp;
  int i = blockIdx.x*blockDim.x + threadIdx.x;
  if(i < T) stf(out, a_base + i, f, ws_alpha[inv[i]]);
}

// ---- GraphNorm apply --------------------------------------------------------
__global__ void k_zero_stats(float* stats){ stats[threadIdx.x] = 0.f; }

__global__ __launch_bounds__(256) void k_gn_apply(
    float* __restrict__ x, const float* __restrict__ stats,
    const void* __restrict__ gw, const void* __restrict__ gb,
    const void* __restrict__ gms, void* __restrict__ out,
    size_t x_base, size_t h_base, const int* __restrict__ flagp,
    int N, int layer, float invN)
{
  const int f = *flagp;
  const int lane = threadIdx.x & 63;
  const size_t pofs = (size_t)layer*64;
  const float mean = stats[lane] * invN;
  const float ex2  = stats[64+lane] * invN;
  const float c    = mean * ldf(gms, pofs + lane, f);
  const float var  = ex2 - 2.f*c*mean + c*c;   // E[(x-c)^2]
  const float a    = ldf(gw, pofs + lane, f) / sqrtf(var + 1e-5f);
  const float bb   = ldf(gb, pofs + lane, f);
  const size_t total = (size_t)N * 64;
  for(size_t idx = (size_t)blockIdx.x*256 + threadIdx.x; idx < total;
      idx += (size_t)gridDim.x*256){
    float v = (x[idx] - c) * a + bb;
    v = lrelu(v, 0.01f);
    x[idx] = v;
    float hv = 0.5f*v + (layer == 0 ? 0.f : ldf(out, h_base + idx, f));
    stf(out, h_base + idx, f, hv);
    if(layer == 3) stf(out, x_base + idx, f, v);
  }
}

// ---- host launch ------------------------------------------------------------
extern "C" void kernel_launch(void* const* d_in, const int* in_sizes, int n_in,
                              void* d_out, int out_size, void* d_ws, size_t ws_size,
                              hipStream_t stream) {
  const void* xf   = d_in[0];
  const int*  ids  = (const int*)d_in[1];
  const int*  eidx = (const int*)d_in[2];
  const void* emb  = d_in[3];
  const void* win  = d_in[4];
  const void* bin  = d_in[5];
  const void* lw   = d_in[6];
  const void* lb   = d_in[7];
  const void* att  = d_in[8];
  const void* cb   = d_in[9];
  const void* gw   = d_in[10];
  const void* gb   = d_in[11];
  const void* gms  = d_in[12];

  const int N = in_sizes[1];
  const int E = in_sizes[2] / 2;
  const int T = E + N;
  const int* srcp = eidx;
  const int* dstp = eidx + E;

  // workspace carve (~73 MB)
  char* p = (char*)d_ws;
  float* x  = (float*)p; p += (size_t)N*64*4;
  float* g  = (float*)p; p += (size_t)N*64*4;
  int* deg  = (int*)p;   p += ((size_t)N*4 + 63) & ~63ull;
  int* off  = (int*)p;   p += ((size_t)N*4 + 63) & ~63ull;
  int* cur  = (int*)p;   p += ((size_t)N*4 + 63) & ~63ull;
  int* inv  = (int*)p;   p += ((size_t)T*4 + 63) & ~63ull;
  int* csrc = (int*)p;   p += ((size_t)T*4 + 63) & ~63ull;
  float* ws_alpha = (float*)p; p += ((size_t)T*4 + 63) & ~63ull;
  int* partial = (int*)p; p += 4096;
  float* stats = (float*)p; p += 512;
  int* flag = (int*)p;    p += 64;

  const size_t x_base = 0;
  const size_t h_base = (size_t)N*64;
  const size_t a_base = (size_t)2*N*64;

  k_detect<<<1, 64, 0, stream>>>((const uint32_t*)xf, flag);
  k_encoder<<<2048, 256, 0, stream>>>(xf, ids, emb, win, bin, x, flag, N);

  k_deg_init <<<(N+255)/256, 256, 0, stream>>>(deg, N);
  k_deg_count<<<(E+255)/256, 256, 0, stream>>>(dstp, deg, E);
  const int nchunks = (N + 1023) / 1024;
  k_scan_partial<<<nchunks, 256, 0, stream>>>(deg, partial, N);
  k_scan_top    <<<1, 1, 0, stream>>>(partial, nchunks);
  k_scan_final  <<<nchunks, 256, 0, stream>>>(deg, partial, off, cur, N);
  k_scatter     <<<(T+255)/256, 256, 0, stream>>>(srcp, dstp, cur, inv, csrc, E, N);

  for(int l = 0; l < 4; l++){
    k_zero_stats<<<1, 128, 0, stream>>>(stats);
    k_linear<<<2048, 256, 0, stream>>>(x, lw, lb, g, flag, l, N);
    k_gat<<<(N+3)/4, 256, 0, stream>>>(g, off, deg, csrc, att, cb, x,
                                       ws_alpha, stats, flag, l, N);
    k_alpha_perm<<<(T+255)/256, 256, 0, stream>>>(ws_alpha, inv, d_out,
                                                  a_base + (size_t)l*T, flag, T);
    k_gn_apply<<<1024, 256, 0, stream>>>(x, stats, gw, gb, gms, d_out,
                                         x_base, h_base, flag, N, l, 1.0f/(float)N);
  }
}